// Round 9
// baseline (261.237 us; speedup 1.0000x reference)
//
#include <hip/hip_runtime.h>
#include <hip/hip_bf16.h>

// TasteNet fused MLP: z(N,64) -> h1(128) relu -> h2(128) relu -> b(12) ->
// clamp/taste/segment-sum epilogue with x(N,9) -> out(N,3) fp32.
//
// R9 vs R8: R8 (AGPR-pinned accs) doubled occupancy to 2 waves/SIMD, 86 us,
// but arch demand ~133 > 128 split -> ~5 dword/lane/iter residual spill
// (WRITE 11.3 vs 6.1 MB) and granule 128+64=192 caps at 2 waves/SIMD.
// R9 cuts arch to ~100 so granule ~148-160 -> 3 waves/SIMD:
//  - z-prefetch ring removed (-32 regs): on-demand z at tile top. Steady
//    state z is L3-resident (FETCH 78 MB < 153 MB footprint), ~300-500 cyc
//    exposure per tile, covered by the added TLP.
//  - x loaded in the epilogue (-5 regs, shorter live ranges).
//  - grid 768 = 3 resident blocks/CU (LDS 3 x 52.8 = 158 <= 160 KB).
// launch_bounds stays (256,2): it's an allocator budget (min-waves), not an
// occupancy cap; actual waves/SIMD = floor(512 / unified granule).

typedef __bf16 bf16x8 __attribute__((ext_vector_type(8)));
typedef float  f32x16 __attribute__((ext_vector_type(16)));
typedef unsigned int uint2v __attribute__((ext_vector_type(2)));
typedef unsigned int uint4v __attribute__((ext_vector_type(4)));

#define MFMA32(a, b, c) __builtin_amdgcn_mfma_f32_32x32x16_bf16((a), (b), (c), 0, 0, 0)
// Pin an f32x16 accumulator into the AGPR half of the unified file (R8 win).
#define PIN_AGPR(v) asm("" : "+a"(v))

// ---- LDS layout (bf16 element offsets), verified R2-R8 ----
#define SW3 0        // 12 rows x 128 elts (row reads m=12..31 overrun into SW1;
                     // garbage feats land in acc3 regs never read)
#define SW1 1536     // 128 rows x 64 elts (128 B row, xor-swizzled 16B chunks)
#define SW2 9728     // 128 rows x 128 elts (256 B row, swizzled)
#define SB1 26112
#define SB2 26240
#define SB3 26368
#define SMEM_ELTS 26384   // 52768 B -> 3 blocks/CU (158.3 KB of 160)

#define NBLK    768
#define NTILE   16384          // 524288 rows / 32
#define WSTRIDE (NBLK * 4)     // 3072 waves, 5-6 tiles each

__device__ __forceinline__ unsigned pkbf(float lo, float hi) {
  unsigned short lb = __builtin_bit_cast(unsigned short, (__bf16)lo);
  unsigned short hb = __builtin_bit_cast(unsigned short, (__bf16)hi);
  return ((unsigned)hb << 16) | (unsigned)lb;
}

// 32x32 C-layout -> next-layer B-frag via one permlane32_swap per packed pair.
// Verified R1-R8 (absmax 5.9e-3).
template <int SUB>
__device__ __forceinline__ bf16x8 mk_bfrag(const f32x16 h) {
  constexpr int B = SUB * 8;
  unsigned p01 = pkbf(h[B + 0], h[B + 1]);
  unsigned p23 = pkbf(h[B + 2], h[B + 3]);
  unsigned p45 = pkbf(h[B + 4], h[B + 5]);
  unsigned p67 = pkbf(h[B + 6], h[B + 7]);
  unsigned d0, d1, d2, d3;
#if __has_builtin(__builtin_amdgcn_permlane32_swap)
  uint2v r1 = __builtin_amdgcn_permlane32_swap(p01, p45, false, false);
  uint2v r2 = __builtin_amdgcn_permlane32_swap(p23, p67, false, false);
  d0 = r1[0]; d2 = r1[1];
  d1 = r2[0]; d3 = r2[1];
#else
  int hi = (threadIdx.x >> 5) & 1;
  unsigned sp01 = (unsigned)__shfl_xor((int)p01, 32, 64);
  unsigned sp23 = (unsigned)__shfl_xor((int)p23, 32, 64);
  unsigned sp45 = (unsigned)__shfl_xor((int)p45, 32, 64);
  unsigned sp67 = (unsigned)__shfl_xor((int)p67, 32, 64);
  d0 = hi ? sp45 : p01;
  d2 = hi ? p45  : sp01;
  d1 = hi ? sp67 : p23;
  d3 = hi ? p67  : sp23;
#endif
  uint4v t; t[0] = d0; t[1] = d1; t[2] = d2; t[3] = d3;
  return __builtin_bit_cast(bf16x8, t);
}

// LDS A-frag read: VGPR addr + compile-time immediate byte offset.
__device__ __forceinline__ bf16x8 ldw(const __bf16* sm, int vaddr, int imm) {
  return *(const bf16x8*)((const char*)sm + vaddr + imm);
}

// bias A-frag: A[m][0] = v on q=0 lanes; MFMA'd against ones-B (B[0][:]=1)
__device__ __forceinline__ bf16x8 biasA(__bf16 v) {
  bf16x8 f;
  #pragma unroll
  for (int i = 0; i < 8; ++i) f[i] = (__bf16)0.0f;
  f[0] = v;
  return f;
}

__global__ __launch_bounds__(256, 2)
void tastenet_kernel(const float* __restrict__ x, const float* __restrict__ z,
                     const float* __restrict__ W1, const float* __restrict__ b1,
                     const float* __restrict__ W2, const float* __restrict__ b2,
                     const float* __restrict__ W3, const float* __restrict__ b3,
                     float* __restrict__ out) {
  __shared__ __align__(16) __bf16 sm[SMEM_ELTS];
  const int tid = threadIdx.x;
  unsigned* smw = (unsigned*)sm;

  // ---- stage weights transposed + bf16, xor-swizzled 16B chunks ----
  for (int i = tid; i < 4096; i += 256) {           // W1 (64x128)
    int m = i & 127, k = (i >> 7) * 2;
    smw[SW1 / 2 + m * 32 + (((k >> 3) ^ (m & 7)) << 2) + ((k >> 1) & 3)] =
        pkbf(W1[k * 128 + m], W1[(k + 1) * 128 + m]);
  }
  for (int i = tid; i < 8192; i += 256) {           // W2 (128x128)
    int m = i & 127, k = (i >> 7) * 2;
    smw[SW2 / 2 + m * 64 + (((k >> 3) ^ (m & 7)) << 2) + ((k >> 1) & 3)] =
        pkbf(W2[k * 128 + m], W2[(k + 1) * 128 + m]);
  }
  for (int i = tid; i < 768; i += 256) {            // W3 (128x12)
    int kk = i / 12, m = i - kk * 12, k = kk * 2;
    smw[SW3 / 2 + m * 64 + (((k >> 3) ^ (m & 7)) << 2) + ((k >> 1) & 3)] =
        pkbf(W3[k * 12 + m], W3[(k + 1) * 12 + m]);
  }
  if (tid < 128) { sm[SB1 + tid] = (__bf16)b1[tid]; sm[SB2 + tid] = (__bf16)b2[tid]; }
  if (tid < 12)  sm[SB3 + tid] = (__bf16)b3[tid];
  __syncthreads();

  const int wave = tid >> 6;
  const int lane = tid & 63;
  const int q    = lane >> 5;
  const int n    = lane & 31;
  const int s8   = n & 7;
  const int eq   = q ^ (s8 & 1);
  const int sh   = s8 >> 1;

  // per-lane swizzled A-frag base addresses (8 regs; strides are immediates)
  int aw1[4], aw2[4];
  #pragma unroll
  for (int j = 0; j < 4; ++j) {
    aw1[j] = n * 128 + eq * 16 + 32 * (j ^ sh);   // W1: 128 B rows
    aw2[j] = n * 256 + eq * 16 + 32 * (j ^ sh);   // W2/W3: 256 B rows
  }

  __bf16 bv1[4], bv2[4], bv3;
  #pragma unroll
  for (int f = 0; f < 4; ++f) {
    bv1[f] = (q == 0) ? sm[SB1 + f * 32 + n] : (__bf16)0.0f;
    bv2[f] = (q == 0) ? sm[SB2 + f * 32 + n] : (__bf16)0.0f;
  }
  bv3 = (q == 0 && n < 12) ? sm[SB3 + n] : (__bf16)0.0f;

  bf16x8 ones;
  #pragma unroll
  for (int i = 0; i < 8; ++i) ones[i] = (__bf16)0.0f;
  if (q == 0) ones[0] = (__bf16)1.0f;

  const int wid = blockIdx.x * 4 + wave;

  #pragma unroll 1
  for (int t = wid; t < NTILE; t += WSTRIDE) {
    const long row = (long)t * 32 + n;

    // ---- on-demand z load (L3-resident in steady state, ~300-500 cyc;
    // covered by 3-waves/SIMD TLP). zt lives only until conversion. ----
    const float* zr = z + row * 64;
    float4 zt[8];
    #pragma unroll
    for (int kt = 0; kt < 4; ++kt) {
      zt[2 * kt]     = *(const float4*)(zr + kt * 16 + q * 8);
      zt[2 * kt + 1] = *(const float4*)(zr + kt * 16 + q * 8 + 4);
    }
    bf16x8 bz[4];
    #pragma unroll
    for (int kt = 0; kt < 4; ++kt) {
      float4 a = zt[2 * kt], b = zt[2 * kt + 1];
      bf16x8 f;
      f[0] = (__bf16)a.x; f[1] = (__bf16)a.y; f[2] = (__bf16)a.z; f[3] = (__bf16)a.w;
      f[4] = (__bf16)b.x; f[5] = (__bf16)b.y; f[6] = (__bf16)b.z; f[7] = (__bf16)b.w;
      bz[kt] = f;
    }

    // ---- layer 1: ft pairs, accumulators pinned to AGPRs ----
    bf16x8 bf2[8];
    #pragma unroll
    for (int fp = 0; fp < 2; ++fp) {
      f32x16 aA, aB;
      #pragma unroll
      for (int i = 0; i < 16; ++i) { aA[i] = 0.0f; aB[i] = 0.0f; }
      PIN_AGPR(aA); PIN_AGPR(aB);
      #pragma unroll
      for (int kt = 0; kt < 4; ++kt) {
        aA = MFMA32(ldw(sm, aw1[kt], SW1 * 2 + (2 * fp + 0) * 4096), bz[kt], aA);
        aB = MFMA32(ldw(sm, aw1[kt], SW1 * 2 + (2 * fp + 1) * 4096), bz[kt], aB);
      }
      aA = MFMA32(biasA(bv1[2 * fp + 0]), ones, aA);
      aB = MFMA32(biasA(bv1[2 * fp + 1]), ones, aB);
      #pragma unroll
      for (int i = 0; i < 16; ++i) { aA[i] = fmaxf(aA[i], 0.0f); aB[i] = fmaxf(aB[i], 0.0f); }
      bf2[4 * fp + 0] = mk_bfrag<0>(aA);
      bf2[4 * fp + 1] = mk_bfrag<1>(aA);
      bf2[4 * fp + 2] = mk_bfrag<0>(aB);
      bf2[4 * fp + 3] = mk_bfrag<1>(aB);
    }

    // ---- layer 2 with layer 3 fused (no bf3 buffer), accs in AGPRs ----
    f32x16 acc3;
    #pragma unroll
    for (int i = 0; i < 16; ++i) acc3[i] = 0.0f;
    PIN_AGPR(acc3);
    #pragma unroll
    for (int fp = 0; fp < 2; ++fp) {
      f32x16 aA, aB;
      #pragma unroll
      for (int i = 0; i < 16; ++i) { aA[i] = 0.0f; aB[i] = 0.0f; }
      PIN_AGPR(aA); PIN_AGPR(aB);
      #pragma unroll
      for (int kt = 0; kt < 8; ++kt) {
        aA = MFMA32(ldw(sm, aw2[kt & 3], SW2 * 2 + (2 * fp + 0) * 8192 + 128 * (kt >> 2)),
                    bf2[kt], aA);
        aB = MFMA32(ldw(sm, aw2[kt & 3], SW2 * 2 + (2 * fp + 1) * 8192 + 128 * (kt >> 2)),
                    bf2[kt], aB);
      }
      aA = MFMA32(biasA(bv2[2 * fp + 0]), ones, aA);
      aB = MFMA32(biasA(bv2[2 * fp + 1]), ones, aB);
      #pragma unroll
      for (int i = 0; i < 16; ++i) { aA[i] = fmaxf(aA[i], 0.0f); aB[i] = fmaxf(aB[i], 0.0f); }
      // h2 features 64*fp + [0,64) == layer-3 K block kt = 4*fp + [0,4)
      acc3 = MFMA32(ldw(sm, aw2[0], SW3 * 2 + 128 * fp), mk_bfrag<0>(aA), acc3);
      acc3 = MFMA32(ldw(sm, aw2[1], SW3 * 2 + 128 * fp), mk_bfrag<1>(aA), acc3);
      acc3 = MFMA32(ldw(sm, aw2[2], SW3 * 2 + 128 * fp), mk_bfrag<0>(aB), acc3);
      acc3 = MFMA32(ldw(sm, aw2[3], SW3 * 2 + 128 * fp), mk_bfrag<1>(aB), acc3);
    }
    acc3 = MFMA32(biasA(bv3), ones, acc3);

    // ---- epilogue: x loaded here (L3-resident; shortest possible live range)
    const float* xr = x + row * 9;
    float t0 = acc3[0], t1 = acc3[1], t2 = acc3[2], t3 = acc3[3];
    float t4 = acc3[4], t5 = acc3[5], t6 = acc3[6], t7 = acc3[7];
    float o0 = 0.f, o1 = 0.f, o2 = 0.f, g1v = 0.f, g2v = 0.f;
    if (q == 0) {
      t0 = fminf(t0, 0.0f); t1 = fminf(t1, 0.0f);
      t2 = fminf(t2, 0.0f); t3 = fminf(t3, 0.0f);
      t4 = fminf(t4, 0.0f);                       // feat 8
      o0 = xr[0] * t0 + xr[1] * t1 + xr[2] * t2 + t5;   // seg0 + I9
      o1 = xr[3] * t3 + t6;                             // seg1 part + I10
      o2 = xr[8] * t4 + t7;                             // seg2 part + I11
    } else {
      t0 = fminf(t0, 0.0f); t1 = fminf(t1, 0.0f); // feats 4,5
      t3 = fminf(t3, 0.0f);                       // feat 7 (feat 6 passes)
      g1v = xr[4] * t0 + xr[5] * t1;
      g2v = xr[6] * t2 + xr[7] * t3;
    }
    float a1v = __shfl_xor(g1v, 32, 64);
    float a2v = __shfl_xor(g2v, 32, 64);
    if (q == 0) {
      float* op = out + row * 3;
      op[0] = o0;
      op[1] = o1 + a1v;
      op[2] = o2 + a2v;
    }
  }
}

extern "C" void kernel_launch(void* const* d_in, const int* in_sizes, int n_in,
                              void* d_out, int out_size, void* d_ws, size_t ws_size,
                              hipStream_t stream) {
  const float* x  = (const float*)d_in[0];
  const float* z  = (const float*)d_in[1];
  const float* W1 = (const float*)d_in[2];
  const float* b1 = (const float*)d_in[3];
  const float* W2 = (const float*)d_in[4];
  const float* b2 = (const float*)d_in[5];
  const float* W3 = (const float*)d_in[6];
  const float* b3 = (const float*)d_in[7];
  tastenet_kernel<<<dim3(NBLK), dim3(256), 0, stream>>>(
      x, z, W1, b1, W2, b2, W3, b3, (float*)d_out);
}

// Round 10
// 234.728 us; speedup vs baseline: 1.1129x; 1.1129x over previous
//
#include <hip/hip_runtime.h>
#include <hip/hip_bf16.h>

// TasteNet fused MLP: z(N,64) -> h1(128) relu -> h2(128) relu -> b(12) ->
// clamp/taste/segment-sum epilogue with x(N,9) -> out(N,3) fp32.
//
// R10 = R8 structure (z-prefetch ring, AGPR-pinned accs, grid 512, (256,2))
// minus its two defects:
//  - zero-C trick: persistent zeroed f32x16 in AGPRs; every chain starts
//    with its bias MFMA (C = zeroC) and accumulates in place. Removes the
//    144 v_accvgpr_write zero-inits per tile (~288 cyc of VALU) that
//    dominated the VALU-bound body (VALUBusy 31% vs MfmaUtil 16%).
//  - bias A-frags + ones B-frag precomputed once, pinned to AGPRs (gfx950
//    MFMA A/B may source AGPRs): kills per-tile frag builds and moves ~10
//    regs off the arch side -> arch ~123 <= 128 split -> R8's residual
//    5-dword spill (WRITE 11.3 vs 6.1 MB) should vanish.
// R9 lesson folded in: granule 180 > 170 means 3 waves/SIMD is out of reach
// without deeper cuts; keep 2 waves/SIMD and spend the round on VALU work.

typedef __bf16 bf16x8 __attribute__((ext_vector_type(8)));
typedef float  f32x16 __attribute__((ext_vector_type(16)));
typedef unsigned int uint2v __attribute__((ext_vector_type(2)));
typedef unsigned int uint4v __attribute__((ext_vector_type(4)));

#define MFMA32(a, b, c) __builtin_amdgcn_mfma_f32_32x32x16_bf16((a), (b), (c), 0, 0, 0)
// Pin a value into the AGPR half of the unified file (R8 win).
#define PIN_AGPR(v) asm("" : "+a"(v))

// ---- LDS layout (bf16 element offsets), verified R2-R9 ----
#define SW3 0        // 12 rows x 128 elts (row reads m=12..31 overrun into SW1;
                     // garbage feats land in acc3 regs never read)
#define SW1 1536     // 128 rows x 64 elts (128 B row, xor-swizzled 16B chunks)
#define SW2 9728     // 128 rows x 128 elts (256 B row, swizzled)
#define SB1 26112
#define SB2 26240
#define SB3 26368
#define SMEM_ELTS 26384   // 52768 B

#define NBLK    512
#define NTILE   16384          // 524288 rows / 32
#define WSTRIDE (NBLK * 4)     // 2048 waves -> exactly 8 tiles each

__device__ __forceinline__ unsigned pkbf(float lo, float hi) {
  unsigned short lb = __builtin_bit_cast(unsigned short, (__bf16)lo);
  unsigned short hb = __builtin_bit_cast(unsigned short, (__bf16)hi);
  return ((unsigned)hb << 16) | (unsigned)lb;
}

// 32x32 C-layout -> next-layer B-frag via one permlane32_swap per packed pair.
// Verified R1-R9 (absmax 5.9e-3).
template <int SUB>
__device__ __forceinline__ bf16x8 mk_bfrag(const f32x16 h) {
  constexpr int B = SUB * 8;
  unsigned p01 = pkbf(h[B + 0], h[B + 1]);
  unsigned p23 = pkbf(h[B + 2], h[B + 3]);
  unsigned p45 = pkbf(h[B + 4], h[B + 5]);
  unsigned p67 = pkbf(h[B + 6], h[B + 7]);
  unsigned d0, d1, d2, d3;
#if __has_builtin(__builtin_amdgcn_permlane32_swap)
  uint2v r1 = __builtin_amdgcn_permlane32_swap(p01, p45, false, false);
  uint2v r2 = __builtin_amdgcn_permlane32_swap(p23, p67, false, false);
  d0 = r1[0]; d2 = r1[1];
  d1 = r2[0]; d3 = r2[1];
#else
  int hi = (threadIdx.x >> 5) & 1;
  unsigned sp01 = (unsigned)__shfl_xor((int)p01, 32, 64);
  unsigned sp23 = (unsigned)__shfl_xor((int)p23, 32, 64);
  unsigned sp45 = (unsigned)__shfl_xor((int)p45, 32, 64);
  unsigned sp67 = (unsigned)__shfl_xor((int)p67, 32, 64);
  d0 = hi ? sp45 : p01;
  d2 = hi ? p45  : sp01;
  d1 = hi ? sp67 : p23;
  d3 = hi ? p67  : sp23;
#endif
  uint4v t; t[0] = d0; t[1] = d1; t[2] = d2; t[3] = d3;
  return __builtin_bit_cast(bf16x8, t);
}

// LDS A-frag read: VGPR addr + compile-time immediate byte offset.
__device__ __forceinline__ bf16x8 ldw(const __bf16* sm, int vaddr, int imm) {
  return *(const bf16x8*)((const char*)sm + vaddr + imm);
}

// bias A-frag: A[m][0] = v on q=0 lanes; MFMA'd against ones-B (B[0][:]=1)
__device__ __forceinline__ bf16x8 biasA(__bf16 v) {
  bf16x8 f;
  #pragma unroll
  for (int i = 0; i < 8; ++i) f[i] = (__bf16)0.0f;
  f[0] = v;
  return f;
}

__global__ __launch_bounds__(256, 2)
void tastenet_kernel(const float* __restrict__ x, const float* __restrict__ z,
                     const float* __restrict__ W1, const float* __restrict__ b1,
                     const float* __restrict__ W2, const float* __restrict__ b2,
                     const float* __restrict__ W3, const float* __restrict__ b3,
                     float* __restrict__ out) {
  __shared__ __align__(16) __bf16 sm[SMEM_ELTS];
  const int tid = threadIdx.x;
  unsigned* smw = (unsigned*)sm;

  // ---- stage weights transposed + bf16, xor-swizzled 16B chunks ----
  for (int i = tid; i < 4096; i += 256) {           // W1 (64x128)
    int m = i & 127, k = (i >> 7) * 2;
    smw[SW1 / 2 + m * 32 + (((k >> 3) ^ (m & 7)) << 2) + ((k >> 1) & 3)] =
        pkbf(W1[k * 128 + m], W1[(k + 1) * 128 + m]);
  }
  for (int i = tid; i < 8192; i += 256) {           // W2 (128x128)
    int m = i & 127, k = (i >> 7) * 2;
    smw[SW2 / 2 + m * 64 + (((k >> 3) ^ (m & 7)) << 2) + ((k >> 1) & 3)] =
        pkbf(W2[k * 128 + m], W2[(k + 1) * 128 + m]);
  }
  for (int i = tid; i < 768; i += 256) {            // W3 (128x12)
    int kk = i / 12, m = i - kk * 12, k = kk * 2;
    smw[SW3 / 2 + m * 64 + (((k >> 3) ^ (m & 7)) << 2) + ((k >> 1) & 3)] =
        pkbf(W3[k * 12 + m], W3[(k + 1) * 12 + m]);
  }
  if (tid < 128) { sm[SB1 + tid] = (__bf16)b1[tid]; sm[SB2 + tid] = (__bf16)b2[tid]; }
  if (tid < 12)  sm[SB3 + tid] = (__bf16)b3[tid];
  __syncthreads();

  const int wave = tid >> 6;
  const int lane = tid & 63;
  const int q    = lane >> 5;
  const int n    = lane & 31;
  const int s8   = n & 7;
  const int eq   = q ^ (s8 & 1);
  const int sh   = s8 >> 1;

  // per-lane swizzled A-frag base addresses (8 regs; strides are immediates)
  int aw1[4], aw2[4];
  #pragma unroll
  for (int j = 0; j < 4; ++j) {
    aw1[j] = n * 128 + eq * 16 + 32 * (j ^ sh);   // W1: 128 B rows
    aw2[j] = n * 256 + eq * 16 + 32 * (j ^ sh);   // W2/W3: 256 B rows
  }

  // ---- persistent operand fragments, all pinned to the AGPR half ----
  bf16x8 ones;
  #pragma unroll
  for (int i = 0; i < 8; ++i) ones[i] = (__bf16)0.0f;
  if (q == 0) ones[0] = (__bf16)1.0f;
  PIN_AGPR(ones);

  bf16x8 ba1[4], ba2[4], ba3;
  #pragma unroll
  for (int f = 0; f < 4; ++f) {
    ba1[f] = biasA((q == 0) ? sm[SB1 + f * 32 + n] : (__bf16)0.0f);
    ba2[f] = biasA((q == 0) ? sm[SB2 + f * 32 + n] : (__bf16)0.0f);
    PIN_AGPR(ba1[f]); PIN_AGPR(ba2[f]);
  }
  ba3 = biasA((q == 0 && n < 12) ? sm[SB3 + n] : (__bf16)0.0f);
  PIN_AGPR(ba3);

  // persistent zero C-operand (AGPR): every MFMA chain starts from this,
  // eliminating per-tile accumulator zero-init VALU work.
  f32x16 zeroC;
  #pragma unroll
  for (int i = 0; i < 16; ++i) zeroC[i] = 0.0f;
  PIN_AGPR(zeroC);

  const int wid = blockIdx.x * 4 + wave;

  // prefetch z for first tile (single ring slot, 32 regs)
  float4 zv[8];
  {
    const float* zr = z + ((long)wid * 32 + n) * 64;
    #pragma unroll
    for (int kt = 0; kt < 4; ++kt) {
      zv[2 * kt]     = *(const float4*)(zr + kt * 16 + q * 8);
      zv[2 * kt + 1] = *(const float4*)(zr + kt * 16 + q * 8 + 4);
    }
  }

  #pragma unroll 1
  for (int t = wid; t < NTILE; t += WSTRIDE) {
    const long row = (long)t * 32 + n;

    // x for this tile: issued before the z-prefetch so the epilogue's x-wait
    // leaves the prefetch outstanding (R8 behavior).
    const float* xr = x + row * 9;
    float xv0 = xr[q * 4 + 0], xv1 = xr[q * 4 + 1];
    float xv2 = xr[q * 4 + 2], xv3 = xr[q * 4 + 3];
    float xv4 = xr[8];

    // z -> bf16 B-frags (frees the zv ring slot)
    bf16x8 bz[4];
    #pragma unroll
    for (int kt = 0; kt < 4; ++kt) {
      float4 a = zv[2 * kt], b = zv[2 * kt + 1];
      bf16x8 f;
      f[0] = (__bf16)a.x; f[1] = (__bf16)a.y; f[2] = (__bf16)a.z; f[3] = (__bf16)a.w;
      f[4] = (__bf16)b.x; f[5] = (__bf16)b.y; f[6] = (__bf16)b.z; f[7] = (__bf16)b.w;
      bz[kt] = f;
    }

    // EARLY prefetch of next tile's z into the just-freed slot.
    if (t + WSTRIDE < NTILE) {
      const float* zr = z + ((long)(t + WSTRIDE) * 32 + n) * 64;
      #pragma unroll
      for (int kt = 0; kt < 4; ++kt) {
        zv[2 * kt]     = *(const float4*)(zr + kt * 16 + q * 8);
        zv[2 * kt + 1] = *(const float4*)(zr + kt * 16 + q * 8 + 4);
      }
    }

    // ---- layer 1: ft pairs; chains start at bias MFMA (C = zeroC) ----
    bf16x8 bf2[8];
    #pragma unroll
    for (int fp = 0; fp < 2; ++fp) {
      f32x16 aA = MFMA32(ba1[2 * fp + 0], ones, zeroC);
      f32x16 aB = MFMA32(ba1[2 * fp + 1], ones, zeroC);
      PIN_AGPR(aA); PIN_AGPR(aB);
      #pragma unroll
      for (int kt = 0; kt < 4; ++kt) {
        aA = MFMA32(ldw(sm, aw1[kt], SW1 * 2 + (2 * fp + 0) * 4096), bz[kt], aA);
        aB = MFMA32(ldw(sm, aw1[kt], SW1 * 2 + (2 * fp + 1) * 4096), bz[kt], aB);
      }
      #pragma unroll
      for (int i = 0; i < 16; ++i) { aA[i] = fmaxf(aA[i], 0.0f); aB[i] = fmaxf(aB[i], 0.0f); }
      bf2[4 * fp + 0] = mk_bfrag<0>(aA);
      bf2[4 * fp + 1] = mk_bfrag<1>(aA);
      bf2[4 * fp + 2] = mk_bfrag<0>(aB);
      bf2[4 * fp + 3] = mk_bfrag<1>(aB);
    }

    // ---- layer 2 (bias-start chains) with layer 3 fused ----
    f32x16 acc3 = MFMA32(ba3, ones, zeroC);
    PIN_AGPR(acc3);
    #pragma unroll
    for (int fp = 0; fp < 2; ++fp) {
      f32x16 aA = MFMA32(ba2[2 * fp + 0], ones, zeroC);
      f32x16 aB = MFMA32(ba2[2 * fp + 1], ones, zeroC);
      PIN_AGPR(aA); PIN_AGPR(aB);
      #pragma unroll
      for (int kt = 0; kt < 8; ++kt) {
        aA = MFMA32(ldw(sm, aw2[kt & 3], SW2 * 2 + (2 * fp + 0) * 8192 + 128 * (kt >> 2)),
                    bf2[kt], aA);
        aB = MFMA32(ldw(sm, aw2[kt & 3], SW2 * 2 + (2 * fp + 1) * 8192 + 128 * (kt >> 2)),
                    bf2[kt], aB);
      }
      #pragma unroll
      for (int i = 0; i < 16; ++i) { aA[i] = fmaxf(aA[i], 0.0f); aB[i] = fmaxf(aB[i], 0.0f); }
      // h2 features 64*fp + [0,64) == layer-3 K block kt = 4*fp + [0,4)
      acc3 = MFMA32(ldw(sm, aw2[0], SW3 * 2 + 128 * fp), mk_bfrag<0>(aA), acc3);
      acc3 = MFMA32(ldw(sm, aw2[1], SW3 * 2 + 128 * fp), mk_bfrag<1>(aA), acc3);
      acc3 = MFMA32(ldw(sm, aw2[2], SW3 * 2 + 128 * fp), mk_bfrag<0>(aB), acc3);
      acc3 = MFMA32(ldw(sm, aw2[3], SW3 * 2 + 128 * fp), mk_bfrag<1>(aB), acc3);
    }

    // ---- epilogue (only regs 0..7 carry real features) ----
    float t0 = acc3[0], t1 = acc3[1], t2 = acc3[2], t3 = acc3[3];
    float t4 = acc3[4], t5 = acc3[5], t6 = acc3[6], t7 = acc3[7];
    float o0 = 0.f, o1 = 0.f, o2 = 0.f, g1v = 0.f, g2v = 0.f;
    if (q == 0) {
      t0 = fminf(t0, 0.0f); t1 = fminf(t1, 0.0f);
      t2 = fminf(t2, 0.0f); t3 = fminf(t3, 0.0f);
      t4 = fminf(t4, 0.0f);                       // feat 8
      o0 = xv0 * t0 + xv1 * t1 + xv2 * t2 + t5;   // seg0 + I9
      o1 = xv3 * t3 + t6;                         // seg1 part + I10
      o2 = xv4 * t4 + t7;                         // seg2 part + I11
    } else {
      t0 = fminf(t0, 0.0f); t1 = fminf(t1, 0.0f); // feats 4,5
      t3 = fminf(t3, 0.0f);                       // feat 7 (feat 6 passes)
      g1v = xv0 * t0 + xv1 * t1;
      g2v = xv2 * t2 + xv3 * t3;
    }
    float a1v = __shfl_xor(g1v, 32, 64);
    float a2v = __shfl_xor(g2v, 32, 64);
    if (q == 0) {
      float* op = out + row * 3;
      op[0] = o0;
      op[1] = o1 + a1v;
      op[2] = o2 + a2v;
    }
  }
}

extern "C" void kernel_launch(void* const* d_in, const int* in_sizes, int n_in,
                              void* d_out, int out_size, void* d_ws, size_t ws_size,
                              hipStream_t stream) {
  const float* x  = (const float*)d_in[0];
  const float* z  = (const float*)d_in[1];
  const float* W1 = (const float*)d_in[2];
  const float* b1 = (const float*)d_in[3];
  const float* W2 = (const float*)d_in[4];
  const float* b2 = (const float*)d_in[5];
  const float* W3 = (const float*)d_in[6];
  const float* b3 = (const float*)d_in[7];
  tastenet_kernel<<<dim3(NBLK), dim3(256), 0, stream>>>(
      x, z, W1, b1, W2, b2, W3, b3, (float*)d_out);
}